// Round 4
// baseline (182.943 us; speedup 1.0000x reference)
//
#include <hip/hip_runtime.h>
#include <math.h>

#define NN 20000
#define EE 320000

using short8 = __attribute__((ext_vector_type(8))) short;
using f32x4  = __attribute__((ext_vector_type(4))) float;

__device__ __forceinline__ unsigned short f2bf(float x) {
    union { float f; unsigned u; } v; v.f = x;
    unsigned r = (v.u + 0x7fffu + ((v.u >> 16) & 1u)) >> 16;
    return (unsigned short)r;
}
__device__ __forceinline__ float bf2f(unsigned short b) {
    union { unsigned u; float f; } v; v.u = ((unsigned)b) << 16;
    return v.f;
}
__device__ __forceinline__ float sigmoidf_(float x) { return 1.f / (1.f + __expf(-x)); }
__device__ __forceinline__ float tanhf_(float x) {
    float e = __expf(-2.f * x);
    return (1.f - e) / (1.f + e);
}
__device__ __forceinline__ float lrelu_(float x) { return x > 0.f ? x : 0.2f * x; }

// ---------------- weight pack into MFMA B-fragment layout ----------------
// mode 0 (K=128): value(tile no, ktile ko, lane l, j) = w[no*16+(l&15)][ko*32+(l>>4)*8+j]
// mode 1: W2b (bond part of fc2_w), K=32 zero-padded, tile t -> ch = (l&15)*8+t
struct PackDesc { const float* w; unsigned short* out; int O; int ldw; int mode; };
struct PackArgs { PackDesc d[10]; };

__global__ void k_pack(PackArgs args) {
    PackDesc d = args.d[blockIdx.y];
    int idx = blockIdx.x * 256 + threadIdx.x;
    if (d.mode == 1) {
        if (idx >= 512) return;
        int t = idx >> 6, l = idx & 63;
        int lr = l & 15, lg = l >> 4;
        int ch = lr * 8 + t;
        short8 o;
        #pragma unroll
        for (int j = 0; j < 8; j++) {
            int k = lg * 8 + j;
            o[j] = (k < 16) ? (short)f2bf(d.w[(size_t)ch * 144 + 128 + k]) : (short)0;
        }
        *(short8*)(d.out + (size_t)idx * 8) = o;
        return;
    }
    int total = (d.O / 16) * 4 * 64;
    if (idx >= total) return;
    int l = idx & 63, rest = idx >> 6;
    int ko = rest & 3, no = rest >> 2;
    int row = no * 16 + (l & 15);
    int col0 = ko * 32 + ((l >> 4) * 8);
    const float* src = d.w + (size_t)row * d.ldw + col0;
    unsigned short o[8];
    #pragma unroll
    for (int j = 0; j < 8; j++) o[j] = f2bf(src[j]);
    #pragma unroll
    for (int j = 0; j < 8; j++) d.out[(size_t)idx * 8 + j] = o[j];
}

// ---------------- V1 front: new_atom=lrelu(fc1(atom)) -> g0,naBf ; U=atom@W2a+b2 ;
//                  nbr_trans=attend(new_atom) ; adst=dot(new_atom, att_w[:128]) -----
__global__ __launch_bounds__(256) void k_v1_front(
    const float* __restrict__ atom,
    const unsigned short* __restrict__ Bfc1, const unsigned short* __restrict__ BW2a,
    const unsigned short* __restrict__ Batt,
    const float* __restrict__ fc1_b, const float* __restrict__ fc2_b,
    const float* __restrict__ attend_b, const float* __restrict__ attw,
    float* __restrict__ g0, unsigned short* __restrict__ naBf,
    unsigned short* __restrict__ Ubf, unsigned short* __restrict__ nbrt,
    float* __restrict__ adst)
{
    __shared__ float Xs[16][132];
    __shared__ unsigned short Ys[16 * 128];
    __shared__ unsigned short Ys2[16 * 128];
    const int tid = threadIdx.x, l = tid & 63, w = tid >> 6;
    const int lr = l & 15, lg = l >> 4;
    const int m0 = blockIdx.x * 16;

    f32x4 acc1[2] = {}, accU[2] = {};
    #pragma unroll
    for (int ko = 0; ko < 4; ko++) {
        const float* ap = atom + (size_t)(m0 + lr) * 128 + ko * 32 + lg * 8;
        float4 a0 = *(const float4*)ap, a1 = *(const float4*)(ap + 4);
        short8 af;
        af[0] = (short)f2bf(a0.x); af[1] = (short)f2bf(a0.y);
        af[2] = (short)f2bf(a0.z); af[3] = (short)f2bf(a0.w);
        af[4] = (short)f2bf(a1.x); af[5] = (short)f2bf(a1.y);
        af[6] = (short)f2bf(a1.z); af[7] = (short)f2bf(a1.w);
        #pragma unroll
        for (int i = 0; i < 2; i++) {
            int t = w * 2 + i;
            short8 b1 = *(const short8*)(Bfc1 + ((size_t)(t * 4 + ko) * 64 + l) * 8);
            acc1[i] = __builtin_amdgcn_mfma_f32_16x16x32_bf16(af, b1, acc1[i], 0, 0, 0);
            short8 bu = *(const short8*)(BW2a + ((size_t)(t * 4 + ko) * 64 + l) * 8);
            accU[i] = __builtin_amdgcn_mfma_f32_16x16x32_bf16(af, bu, accU[i], 0, 0, 0);
        }
    }
    #pragma unroll
    for (int i = 0; i < 2; i++) {
        int col = (w * 2 + i) * 16 + lr;
        float b1v = fc1_b[col], bUv = fc2_b[col];
        #pragma unroll
        for (int r = 0; r < 4; r++) {
            int row = lg * 4 + r;
            float v = lrelu_(acc1[i][r] + b1v);
            Xs[row][col] = v;
            g0[(size_t)(m0 + row) * 128 + col] = v;
            Ys2[row * 128 + col] = f2bf(accU[i][r] + bUv);
        }
    }
    __syncthreads();
    *(short8*)(Ubf + (size_t)m0 * 128 + tid * 8) = *(const short8*)(Ys2 + tid * 8);
    {
        int row = tid >> 4, q = tid & 15;
        short8 tmp;
        float p = 0.f;
        #pragma unroll
        for (int j = 0; j < 8; j++) {
            float x = Xs[row][q * 8 + j];
            tmp[j] = (short)f2bf(x);
            p = fmaf(x, attw[q * 8 + j], p);
        }
        *(short8*)(naBf + (size_t)(m0 + row) * 128 + q * 8) = tmp;
        #pragma unroll
        for (int m = 1; m <= 8; m <<= 1) p += __shfl_xor(p, m, 16);
        if (q == 0) adst[m0 + row] = p;
    }
    f32x4 acc2[2] = {};
    #pragma unroll
    for (int ko = 0; ko < 4; ko++) {
        short8 af;
        const float* xp = &Xs[lr][ko * 32 + lg * 8];
        #pragma unroll
        for (int j = 0; j < 8; j++) af[j] = (short)f2bf(xp[j]);
        #pragma unroll
        for (int i = 0; i < 2; i++) {
            int t = w * 2 + i;
            short8 bf = *(const short8*)(Batt + ((size_t)(t * 4 + ko) * 64 + l) * 8);
            acc2[i] = __builtin_amdgcn_mfma_f32_16x16x32_bf16(af, bf, acc2[i], 0, 0, 0);
        }
    }
    #pragma unroll
    for (int i = 0; i < 2; i++) {
        int col = (w * 2 + i) * 16 + lr;
        float bb = attend_b[col];
        #pragma unroll
        for (int r = 0; r < 4; r++)
            Ys[(lg * 4 + r) * 128 + col] = f2bf(acc2[i][r] + bb);
    }
    __syncthreads();
    *(short8*)(nbrt + (size_t)m0 * 128 + tid * 8) = *(const short8*)(Ys + tid * 8);
}

// ---------------- mega GRU kernel ----------------
// AGG=2: V1 edge logits (bond MFMA + U decomposition) + softmax + gather -> ctxS
// AGG=1: V2 logits (aD[dst]+bS[src]) + softmax + gather -> ctxS
// then GRU (fragment-domain gates); FRONT: next layer's nt/aD/bS; FINAL: avg+lin+gelu.
template<int AGG, int FRONT, int FINAL>
__global__ __launch_bounds__(256) void k_gru(
    const unsigned short* __restrict__ U, const float* __restrict__ bond,
    const unsigned short* __restrict__ BW2b, const float* __restrict__ attw,
    const float* __restrict__ attb1, const float* __restrict__ adstV1,
    const float* __restrict__ aD, const float* __restrict__ bS,
    const float* __restrict__ bias1,
    const int* __restrict__ esrc, const unsigned short* __restrict__ V,
    const unsigned short* __restrict__ hBf,
    const unsigned short* __restrict__ Bih, const unsigned short* __restrict__ Bhh,
    const float* __restrict__ bih, const float* __restrict__ bhh,
    const float* __restrict__ hprevF, float* __restrict__ houtF,
    unsigned short* __restrict__ houtBf,
    const unsigned short* __restrict__ Bfc2, const float* __restrict__ fc2b,
    const float* __restrict__ w2att, unsigned short* __restrict__ ntOut,
    float* __restrict__ aDOut, float* __restrict__ bSOut,
    const float* __restrict__ as0, const float* __restrict__ as1,
    const unsigned short* __restrict__ Blin, const float* __restrict__ linb,
    float* __restrict__ avgOut, float* __restrict__ outF)
{
    __shared__ unsigned short ctxS[16][136];
    __shared__ unsigned short Ys[16 * 128];
    const int tid = threadIdx.x, l = tid & 63, w = tid >> 6;
    const int lr = l & 15, lg = l >> 4;
    const int m0 = blockIdx.x * 16;

    if (AGG == 2) {
        // hoisted W2b B-frags + att weights
        short8 bw[8];
        #pragma unroll
        for (int t = 0; t < 8; t++)
            bw[t] = *(const short8*)(BW2b + (size_t)(t * 64 + l) * 8);
        float aw[8];
        #pragma unroll
        for (int t = 0; t < 8; t++) aw[t] = attw[128 + lr * 8 + t];
        const float ab = attb1[0];
        #pragma unroll
        for (int nn = 0; nn < 4; nn++) {
            const int n = m0 + w * 4 + nn;
            const int e0 = n * 16;
            short8 af = {};
            if (lg < 2) {
                const float* bp = bond + (size_t)(e0 + lr) * 16 + lg * 8;
                float4 b0 = *(const float4*)bp, b1 = *(const float4*)(bp + 4);
                af[0] = (short)f2bf(b0.x); af[1] = (short)f2bf(b0.y);
                af[2] = (short)f2bf(b0.z); af[3] = (short)f2bf(b0.w);
                af[4] = (short)f2bf(b1.x); af[5] = (short)f2bf(b1.y);
                af[6] = (short)f2bf(b1.z); af[7] = (short)f2bf(b1.w);
            }
            f32x4 c[8];
            #pragma unroll
            for (int t = 0; t < 8; t++) {
                f32x4 z = {};
                c[t] = __builtin_amdgcn_mfma_f32_16x16x32_bf16(af, bw[t], z, 0, 0, 0);
            }
            int srcs[4];
            float ex[4];
            #pragma unroll
            for (int r = 0; r < 4; r++) {
                int e = e0 + lg * 4 + r;
                int src = esrc[e];
                srcs[r] = src;
                short8 u = *(const short8*)(U + (size_t)src * 128 + lr * 8);
                float s = 0.f;
                #pragma unroll
                for (int t = 0; t < 8; t++)
                    s = fmaf(aw[t], lrelu_(c[t][r] + bf2f((unsigned short)u[t])), s);
                ex[r] = s;
            }
            #pragma unroll
            for (int mk = 1; mk <= 8; mk <<= 1)
                #pragma unroll
                for (int r = 0; r < 4; r++) ex[r] += __shfl_xor(ex[r], mk, 16);
            float anode = adstV1[n];
            float li[4];
            #pragma unroll
            for (int r = 0; r < 4; r++) li[r] = lrelu_(anode + ab + ex[r]);
            float mx = fmaxf(fmaxf(li[0], li[1]), fmaxf(li[2], li[3]));
            mx = fmaxf(mx, __shfl_xor(mx, 16));
            mx = fmaxf(mx, __shfl_xor(mx, 32));
            float ds = 0.f;
            #pragma unroll
            for (int r = 0; r < 4; r++) { ex[r] = __expf(li[r] - mx); ds += ex[r]; }
            ds += __shfl_xor(ds, 16);
            ds += __shfl_xor(ds, 32);
            float inv = 1.f / ds;
            float c0 = 0.f, c1 = 0.f;
            #pragma unroll
            for (int i = 0; i < 16; i++) {
                const int rr = i & 3, gg = i >> 2;
                float wi = __shfl(ex[rr], gg * 16, 64) * inv;
                int src = __shfl(srcs[rr], gg * 16, 64);
                unsigned vv = *(const unsigned*)(V + (size_t)src * 128 + l * 2);
                c0 = fmaf(wi, bf2f((unsigned short)(vv & 0xffffu)), c0);
                c1 = fmaf(wi, bf2f((unsigned short)(vv >> 16)), c1);
            }
            c0 = c0 > 0.f ? c0 : __expf(c0) - 1.f;
            c1 = c1 > 0.f ? c1 : __expf(c1) - 1.f;
            unsigned o = (unsigned)f2bf(c0) | ((unsigned)f2bf(c1) << 16);
            *(unsigned*)&ctxS[w * 4 + nn][l * 2] = o;
        }
        __syncthreads();
    }
    if (AGG == 1) {
        const int t = tid >> 4, q = tid & 15;
        const int node = m0 + t;
        int srcq = esrc[node * 16 + q];
        float lg0 = lrelu_(aD[node] + bS[srcq] + bias1[0]);
        float mx = lg0;
        #pragma unroll
        for (int mk = 1; mk <= 8; mk <<= 1) mx = fmaxf(mx, __shfl_xor(mx, mk, 16));
        float ex = __expf(lg0 - mx);
        float den = ex;
        #pragma unroll
        for (int mk = 1; mk <= 8; mk <<= 1) den += __shfl_xor(den, mk, 16);
        float wq = ex / den;
        float s[8] = {};
        #pragma unroll
        for (int i = 0; i < 16; i++) {
            float wi = __shfl(wq, i, 16);
            int src = __shfl(srcq, i, 16);
            short8 vv = *(const short8*)(V + (size_t)src * 128 + q * 8);
            #pragma unroll
            for (int j = 0; j < 8; j++) s[j] = fmaf(wi, bf2f((unsigned short)vv[j]), s[j]);
        }
        short8 cv;
        #pragma unroll
        for (int j = 0; j < 8; j++) {
            float v = s[j];
            v = v > 0.f ? v : __expf(v) - 1.f;
            cv[j] = (short)f2bf(v);
        }
        *(short8*)&ctxS[t][q * 8] = cv;
        __syncthreads();
    }

    // ---- GRU GEMMs ----
    f32x4 acc[12] = {};
    #pragma unroll
    for (int ko = 0; ko < 4; ko++) {
        short8 afc = *(const short8*)&ctxS[lr][ko * 32 + lg * 8];
        short8 afh = *(const short8*)(hBf + (size_t)(m0 + lr) * 128 + ko * 32 + lg * 8);
        #pragma unroll
        for (int i2 = 0; i2 < 6; i2++) {
            short8 bf = *(const short8*)(Bih + ((size_t)((w + 4 * i2) * 4 + ko) * 64 + l) * 8);
            acc[i2] = __builtin_amdgcn_mfma_f32_16x16x32_bf16(afc, bf, acc[i2], 0, 0, 0);
        }
        #pragma unroll
        for (int i2 = 0; i2 < 6; i2++) {
            short8 bf = *(const short8*)(Bhh + ((size_t)((w + 4 * i2) * 4 + ko) * 64 + l) * 8);
            acc[6 + i2] = __builtin_amdgcn_mfma_f32_16x16x32_bf16(afh, bf, acc[6 + i2], 0, 0, 0);
        }
    }
    // ---- gates (fragment domain) ----
    float hov[2][4];
    #pragma unroll
    for (int i = 0; i < 2; i++) {
        const int c = (w + 4 * i) * 16 + lr;
        const float br = bih[c] + bhh[c];
        const float bz = bih[c + 128] + bhh[c + 128];
        const float bin_ = bih[c + 256];
        const float bhn = bhh[c + 256];
        #pragma unroll
        for (int r = 0; r < 4; r++) {
            const int row = m0 + lg * 4 + r;
            float rg = sigmoidf_(acc[i][r] + acc[6 + i][r] + br);
            float zg = sigmoidf_(acc[i + 2][r] + acc[8 + i][r] + bz);
            float ng = tanhf_(acc[i + 4][r] + bin_ + rg * (acc[10 + i][r] + bhn));
            float hp = hprevF[(size_t)row * 128 + c];
            float ho = fmaf(zg, hp - ng, ng);
            hov[i][r] = ho;
            houtF[(size_t)row * 128 + c] = ho;
            if (FINAL == 0) houtBf[(size_t)row * 128 + c] = f2bf(ho);
        }
    }

    if (FRONT) {
        __syncthreads();   // all ctxS reads done
        #pragma unroll
        for (int i = 0; i < 2; i++) {
            const int c = (w + 4 * i) * 16 + lr;
            #pragma unroll
            for (int r = 0; r < 4; r++) ctxS[lg * 4 + r][c] = f2bf(hov[i][r]);
        }
        __syncthreads();
        {
            int row = tid >> 4, q = tid & 15;
            short8 hv = *(const short8*)&ctxS[row][q * 8];
            float pa = 0.f, pb = 0.f;
            #pragma unroll
            for (int j = 0; j < 8; j++) {
                float x = bf2f((unsigned short)hv[j]);
                pa = fmaf(x, w2att[q * 8 + j], pa);
                pb = fmaf(x, w2att[128 + q * 8 + j], pb);
            }
            #pragma unroll
            for (int m = 1; m <= 8; m <<= 1) {
                pa += __shfl_xor(pa, m, 16);
                pb += __shfl_xor(pb, m, 16);
            }
            if (q == 0) { aDOut[m0 + row] = pa; bSOut[m0 + row] = pb; }
        }
        f32x4 acc2[2] = {};
        #pragma unroll
        for (int ko = 0; ko < 4; ko++) {
            short8 af = *(const short8*)&ctxS[lr][ko * 32 + lg * 8];
            #pragma unroll
            for (int i = 0; i < 2; i++) {
                int t = w * 2 + i;
                short8 bf = *(const short8*)(Bfc2 + ((size_t)(t * 4 + ko) * 64 + l) * 8);
                acc2[i] = __builtin_amdgcn_mfma_f32_16x16x32_bf16(af, bf, acc2[i], 0, 0, 0);
            }
        }
        #pragma unroll
        for (int i = 0; i < 2; i++) {
            int col = (w * 2 + i) * 16 + lr;
            float bb = fc2b[col];
            #pragma unroll
            for (int r = 0; r < 4; r++)
                Ys[(lg * 4 + r) * 128 + col] = f2bf(acc2[i][r] + bb);
        }
        __syncthreads();
        *(short8*)(ntOut + (size_t)m0 * 128 + tid * 8) = *(const short8*)(Ys + tid * 8);
    }

    if (FINAL) {
        __syncthreads();   // all ctxS reads done
        #pragma unroll
        for (int i = 0; i < 2; i++) {
            const int c = (w + 4 * i) * 16 + lr;
            #pragma unroll
            for (int r = 0; r < 4; r++) {
                const int grow = m0 + lg * 4 + r;
                float av = (as0[(size_t)grow * 128 + c] + as1[(size_t)grow * 128 + c]
                            + hov[i][r]) * (1.f / 3.f);
                avgOut[(size_t)grow * 128 + c] = av;
                ctxS[lg * 4 + r][c] = f2bf(av);
            }
        }
        __syncthreads();
        f32x4 acc2[2] = {};
        #pragma unroll
        for (int ko = 0; ko < 4; ko++) {
            short8 af = *(const short8*)&ctxS[lr][ko * 32 + lg * 8];
            #pragma unroll
            for (int i = 0; i < 2; i++) {
                int t = w * 2 + i;
                short8 bf = *(const short8*)(Blin + ((size_t)(t * 4 + ko) * 64 + l) * 8);
                acc2[i] = __builtin_amdgcn_mfma_f32_16x16x32_bf16(af, bf, acc2[i], 0, 0, 0);
            }
        }
        #pragma unroll
        for (int i = 0; i < 2; i++) {
            int col = (w * 2 + i) * 16 + lr;
            float bb = linb[col];
            #pragma unroll
            for (int r = 0; r < 4; r++) {
                float vv = acc2[i][r] + bb;
                vv = 0.5f * vv * (1.f + erff(vv * 0.70710678118654752f));
                outF[(size_t)(m0 + lg * 4 + r) * 128 + col] = vv;
            }
        }
    }
}

extern "C" void kernel_launch(void* const* d_in, const int* in_sizes, int n_in,
                              void* d_out, int out_size, void* d_ws, size_t ws_size,
                              hipStream_t stream) {
    const float* atom     = (const float*)d_in[0];
    const int*   esrc     = (const int*)d_in[1];
    const float* bond     = (const float*)d_in[3];
    const float* fc1_w    = (const float*)d_in[4];
    const float* fc1_b    = (const float*)d_in[5];
    const float* fc2_w    = (const float*)d_in[6];
    const float* fc2_b    = (const float*)d_in[7];
    const float* att_w    = (const float*)d_in[8];
    const float* att_b    = (const float*)d_in[9];
    const float* attend_w = (const float*)d_in[10];
    const float* attend_b = (const float*)d_in[11];
    const float* gih1     = (const float*)d_in[12];
    const float* ghh1     = (const float*)d_in[13];
    const float* bih1     = (const float*)d_in[14];
    const float* bhh1     = (const float*)d_in[15];
    const float* fc1v2_w  = (const float*)d_in[16];
    const float* fc1v2_b  = (const float*)d_in[17];
    const float* fc2v2_w  = (const float*)d_in[18];
    const float* fc2v2_b  = (const float*)d_in[19];
    const float* gih2     = (const float*)d_in[20];
    const float* ghh2     = (const float*)d_in[21];
    const float* bih2     = (const float*)d_in[22];
    const float* bhh2     = (const float*)d_in[23];
    const float* lin_w    = (const float*)d_in[24];
    const float* lin_b    = (const float*)d_in[25];

    char* wsb = (char*)d_ws;
    size_t off = 0;
    auto allocB = [&](size_t bytes) {
        size_t o = off; off = (off + bytes + 255) & ~(size_t)255; return o;
    };
    unsigned short* Bfc1   = (unsigned short*)(wsb + allocB(128 * 128 * 2));
    unsigned short* Batt   = (unsigned short*)(wsb + allocB(128 * 128 * 2));
    unsigned short* BW2a   = (unsigned short*)(wsb + allocB(128 * 128 * 2));
    unsigned short* BW2b   = (unsigned short*)(wsb + allocB(512 * 8 * 2));
    unsigned short* Bgih1  = (unsigned short*)(wsb + allocB(384 * 128 * 2));
    unsigned short* Bghh1  = (unsigned short*)(wsb + allocB(384 * 128 * 2));
    unsigned short* Bfc2v2 = (unsigned short*)(wsb + allocB(128 * 128 * 2));
    unsigned short* Bgih2  = (unsigned short*)(wsb + allocB(384 * 128 * 2));
    unsigned short* Bghh2  = (unsigned short*)(wsb + allocB(384 * 128 * 2));
    unsigned short* Blin   = (unsigned short*)(wsb + allocB(128 * 128 * 2));
    unsigned short* naBf   = (unsigned short*)(wsb + allocB((size_t)NN * 128 * 2));
    unsigned short* Ubf    = (unsigned short*)(wsb + allocB((size_t)NN * 128 * 2));
    unsigned short* nbrt   = (unsigned short*)(wsb + allocB((size_t)NN * 128 * 2));
    unsigned short* ntA    = (unsigned short*)(wsb + allocB((size_t)NN * 128 * 2));
    unsigned short* ntB    = (unsigned short*)(wsb + allocB((size_t)NN * 128 * 2));
    unsigned short* h1Bf   = (unsigned short*)(wsb + allocB((size_t)NN * 128 * 2));
    unsigned short* h2Bf   = (unsigned short*)(wsb + allocB((size_t)NN * 128 * 2));
    float* adst = (float*)(wsb + allocB((size_t)NN * 4));
    float* aDA  = (float*)(wsb + allocB((size_t)NN * 4));
    float* bSA  = (float*)(wsb + allocB((size_t)NN * 4));
    float* aDB  = (float*)(wsb + allocB((size_t)NN * 4));
    float* bSB  = (float*)(wsb + allocB((size_t)NN * 4));
    (void)ws_size;

    float* out0 = (float*)d_out;
    float* as0  = out0 + (size_t)NN * 128;
    float* as1  = as0 + (size_t)NN * 128;
    float* as2  = as1 + (size_t)NN * 128;
    float* g0   = out0 + (size_t)4 * NN * 128;
    float* avg  = out0 + (size_t)5 * NN * 128;

    PackArgs pa;
    pa.d[0] = { fc1_w,    Bfc1,   128, 128, 0 };
    pa.d[1] = { attend_w, Batt,   128, 128, 0 };
    pa.d[2] = { fc2_w,    BW2a,   128, 144, 0 };
    pa.d[3] = { gih1,     Bgih1,  384, 128, 0 };
    pa.d[4] = { ghh1,     Bghh1,  384, 128, 0 };
    pa.d[5] = { fc2v2_w,  Bfc2v2, 128, 128, 0 };
    pa.d[6] = { gih2,     Bgih2,  384, 128, 0 };
    pa.d[7] = { ghh2,     Bghh2,  384, 128, 0 };
    pa.d[8] = { lin_w,    Blin,   128, 128, 0 };
    pa.d[9] = { fc2_w,    BW2b,   0,   0,   1 };
    k_pack<<<dim3(24, 10), 256, 0, stream>>>(pa);

    const int GB = NN / 16;  // 1250

    // ---- V1 front ----
    k_v1_front<<<GB, 256, 0, stream>>>(atom, Bfc1, BW2a, Batt, fc1_b, fc2_b,
                                       attend_b, att_w, g0, naBf, Ubf, nbrt, adst);
    // ---- V1 agg + GRU1 + front(layer2) ----
    k_gru<2, 1, 0><<<GB, 256, 0, stream>>>(
        Ubf, bond, BW2b, att_w, att_b, adst,
        nullptr, nullptr, nullptr,
        esrc, nbrt,
        naBf, Bgih1, Bghh1, bih1, bhh1, g0, as0, h1Bf,
        Bfc2v2, fc2v2_b, fc1v2_w, ntA, aDA, bSA,
        nullptr, nullptr, nullptr, nullptr, nullptr, nullptr);
    // ---- V2 layer2: agg + GRU + front(layer3) ----
    k_gru<1, 1, 0><<<GB, 256, 0, stream>>>(
        nullptr, nullptr, nullptr, nullptr, nullptr, nullptr,
        aDA, bSA, fc1v2_b,
        esrc, ntA,
        h1Bf, Bgih2, Bghh2, bih2, bhh2, as0, as1, h2Bf,
        Bfc2v2, fc2v2_b, fc1v2_w, ntB, aDB, bSB,
        nullptr, nullptr, nullptr, nullptr, nullptr, nullptr);
    // ---- V2 layer3: agg + GRU + final (avg+lin+gelu) ----
    k_gru<1, 0, 1><<<GB, 256, 0, stream>>>(
        nullptr, nullptr, nullptr, nullptr, nullptr, nullptr,
        aDB, bSB, fc1v2_b,
        esrc, ntB,
        h2Bf, Bgih2, Bghh2, bih2, bhh2, as1, as2, nullptr,
        nullptr, nullptr, nullptr, nullptr, nullptr, nullptr,
        as0, as1, Blin, lin_b, avg, out0);
}

// Round 5
// 170.204 us; speedup vs baseline: 1.0748x; 1.0748x over previous
//
#include <hip/hip_runtime.h>
#include <math.h>

#define NN 20000
#define EE 320000

using short8 = __attribute__((ext_vector_type(8))) short;
using f32x4  = __attribute__((ext_vector_type(4))) float;
using u16x4  = __attribute__((ext_vector_type(4))) unsigned short;

__device__ __forceinline__ unsigned short f2bf(float x) {
    union { float f; unsigned u; } v; v.f = x;
    unsigned r = (v.u + 0x7fffu + ((v.u >> 16) & 1u)) >> 16;
    return (unsigned short)r;
}
__device__ __forceinline__ float bf2f(unsigned short b) {
    union { unsigned u; float f; } v; v.u = ((unsigned)b) << 16;
    return v.f;
}
__device__ __forceinline__ float sigmoidf_(float x) { return 1.f / (1.f + __expf(-x)); }
__device__ __forceinline__ float tanhf_(float x) {
    float e = __expf(-2.f * x);
    return (1.f - e) / (1.f + e);
}
__device__ __forceinline__ float lrelu_(float x) { return x > 0.f ? x : 0.2f * x; }
__device__ __forceinline__ float elu_(float x) { return x > 0.f ? x : __expf(x) - 1.f; }

// ---------------- weight pack into MFMA B-fragment layout ----------------
struct PackDesc { const float* w; unsigned short* out; int O; int ldw; int mode; };
struct PackArgs { PackDesc d[10]; };

__global__ void k_pack(PackArgs args) {
    PackDesc d = args.d[blockIdx.y];
    int idx = blockIdx.x * 256 + threadIdx.x;
    if (d.mode == 1) {   // W2b: bond part of fc2_w, K=32 zero-padded
        if (idx >= 512) return;
        int t = idx >> 6, l = idx & 63;
        int lr = l & 15, lg = l >> 4;
        int ch = lr * 8 + t;
        short8 o;
        #pragma unroll
        for (int j = 0; j < 8; j++) {
            int k = lg * 8 + j;
            o[j] = (k < 16) ? (short)f2bf(d.w[(size_t)ch * 144 + 128 + k]) : (short)0;
        }
        *(short8*)(d.out + (size_t)idx * 8) = o;
        return;
    }
    int total = (d.O / 16) * 4 * 64;
    if (idx >= total) return;
    int l = idx & 63, rest = idx >> 6;
    int ko = rest & 3, no = rest >> 2;
    int row = no * 16 + (l & 15);
    int col0 = ko * 32 + ((l >> 4) * 8);
    const float* src = d.w + (size_t)row * d.ldw + col0;
    unsigned short o[8];
    #pragma unroll
    for (int j = 0; j < 8; j++) o[j] = f2bf(src[j]);
    #pragma unroll
    for (int j = 0; j < 8; j++) d.out[(size_t)idx * 8 + j] = o[j];
}

// ---------------- V1 front: new_atom=lrelu(fc1(atom)) -> g0,naBf ; U=atom@W2a+b2 ;
//                  adst=dot(new_atom, att_w[:128]) ----------------
__global__ __launch_bounds__(256) void k_v1_front(
    const float* __restrict__ atom,
    const unsigned short* __restrict__ Bfc1, const unsigned short* __restrict__ BW2a,
    const float* __restrict__ fc1_b, const float* __restrict__ fc2_b,
    const float* __restrict__ attw,
    float* __restrict__ g0, unsigned short* __restrict__ naBf,
    unsigned short* __restrict__ Ubf, float* __restrict__ adst)
{
    __shared__ float Xs[16][132];
    __shared__ unsigned short Ys2[16 * 128];
    const int tid = threadIdx.x, l = tid & 63, w = tid >> 6;
    const int lr = l & 15, lg = l >> 4;
    const int m0 = blockIdx.x * 16;

    f32x4 acc1[2] = {}, accU[2] = {};
    #pragma unroll
    for (int ko = 0; ko < 4; ko++) {
        const f32x4* ap = (const f32x4*)(atom + (size_t)(m0 + lr) * 128 + ko * 32 + lg * 8);
        f32x4 a0 = __builtin_nontemporal_load(ap);
        f32x4 a1 = __builtin_nontemporal_load(ap + 1);
        short8 af;
        #pragma unroll
        for (int j = 0; j < 4; j++) { af[j] = (short)f2bf(a0[j]); af[4 + j] = (short)f2bf(a1[j]); }
        #pragma unroll
        for (int i = 0; i < 2; i++) {
            int t = w * 2 + i;
            short8 b1 = *(const short8*)(Bfc1 + ((size_t)(t * 4 + ko) * 64 + l) * 8);
            acc1[i] = __builtin_amdgcn_mfma_f32_16x16x32_bf16(af, b1, acc1[i], 0, 0, 0);
            short8 bu = *(const short8*)(BW2a + ((size_t)(t * 4 + ko) * 64 + l) * 8);
            accU[i] = __builtin_amdgcn_mfma_f32_16x16x32_bf16(af, bu, accU[i], 0, 0, 0);
        }
    }
    #pragma unroll
    for (int i = 0; i < 2; i++) {
        int col = (w * 2 + i) * 16 + lr;
        float b1v = fc1_b[col], bUv = fc2_b[col];
        #pragma unroll
        for (int r = 0; r < 4; r++) {
            int row = lg * 4 + r;
            float v = lrelu_(acc1[i][r] + b1v);
            Xs[row][col] = v;
            __builtin_nontemporal_store(v, g0 + (size_t)(m0 + row) * 128 + col);
            Ys2[row * 128 + col] = f2bf(accU[i][r] + bUv);
        }
    }
    __syncthreads();
    *(short8*)(Ubf + (size_t)m0 * 128 + tid * 8) = *(const short8*)(Ys2 + tid * 8);
    {
        int row = tid >> 4, q = tid & 15;
        short8 tmp;
        float p = 0.f;
        #pragma unroll
        for (int j = 0; j < 8; j++) {
            float x = Xs[row][q * 8 + j];
            tmp[j] = (short)f2bf(x);
            p = fmaf(x, attw[q * 8 + j], p);
        }
        *(short8*)(naBf + (size_t)(m0 + row) * 128 + q * 8) = tmp;
        #pragma unroll
        for (int m = 1; m <= 8; m <<= 1) p += __shfl_xor(p, m, 16);
        if (q == 0) adst[m0 + row] = p;
    }
}

// ---------------- V1 edge logits: bond MFMA + U gather -> logits (lrelu'd) --------
__global__ __launch_bounds__(256) void k_logits_v1(
    const unsigned short* __restrict__ U, const int* __restrict__ esrc,
    const float* __restrict__ bond, const unsigned short* __restrict__ BW2b,
    const float* __restrict__ attw, const float* __restrict__ attb1,
    const float* __restrict__ adst, float* __restrict__ logits)
{
    const int tid = threadIdx.x, l = tid & 63, w = tid >> 6;
    const int lr = l & 15, lg = l >> 4;
    const int n = blockIdx.x * 4 + w;
    const int e0 = n * 16;

    short8 af = {};
    if (lg < 2) {
        const f32x4* bp = (const f32x4*)(bond + (size_t)(e0 + lr) * 16 + lg * 8);
        f32x4 b0 = __builtin_nontemporal_load(bp);
        f32x4 b1 = __builtin_nontemporal_load(bp + 1);
        #pragma unroll
        for (int j = 0; j < 4; j++) { af[j] = (short)f2bf(b0[j]); af[4 + j] = (short)f2bf(b1[j]); }
    }
    f32x4 c[8];
    #pragma unroll
    for (int t = 0; t < 8; t++) {
        short8 bf = *(const short8*)(BW2b + (size_t)(t * 64 + l) * 8);
        f32x4 z = {};
        c[t] = __builtin_amdgcn_mfma_f32_16x16x32_bf16(af, bf, z, 0, 0, 0);
    }
    float aw[8];
    #pragma unroll
    for (int t = 0; t < 8; t++) aw[t] = attw[128 + lr * 8 + t];

    float s[4];
    #pragma unroll
    for (int r = 0; r < 4; r++) {
        int e = e0 + lg * 4 + r;
        int src = esrc[e];
        short8 u = *(const short8*)(U + (size_t)src * 128 + lr * 8);
        float a0 = 0.f;
        #pragma unroll
        for (int t = 0; t < 8; t++)
            a0 = fmaf(aw[t], lrelu_(c[t][r] + bf2f((unsigned short)u[t])), a0);
        s[r] = a0;
    }
    #pragma unroll
    for (int mk = 1; mk <= 8; mk <<= 1)
        #pragma unroll
        for (int r = 0; r < 4; r++) s[r] += __shfl_xor(s[r], mk, 16);
    if (lr == 0) {
        float anode = adst[n], ab = attb1[0];
        f32x4 o;
        #pragma unroll
        for (int r = 0; r < 4; r++) o[r] = lrelu_(anode + ab + s[r]);
        __builtin_nontemporal_store(o, (f32x4*)(logits + e0 + lg * 4));
    }
}

// ---------------- aggregation pass: softmax + gather HALF of channels -------------
// MODE 0: logits from buffer (V1). MODE 1: inline logits aD[dst]+bS[src]+b (V2).
template<int MODE, int HALF>
__global__ __launch_bounds__(256) void k_agg(
    const float* __restrict__ logits, const float* __restrict__ aD,
    const float* __restrict__ bS, const float* __restrict__ b1,
    const int* __restrict__ esrc, const unsigned short* __restrict__ V,
    unsigned short* __restrict__ agg)
{
    const int tid = threadIdx.x;
    const int node = blockIdx.x * 16 + (tid >> 4);
    const int q = tid & 15;
    const int e = node * 16 + q;
    const int src = esrc[e];
    float lgt;
    if (MODE == 0) lgt = logits[e];
    else           lgt = lrelu_(aD[node] + bS[src] + b1[0]);
    float mx = lgt;
    #pragma unroll
    for (int mk = 1; mk <= 8; mk <<= 1) mx = fmaxf(mx, __shfl_xor(mx, mk, 16));
    float ex = __expf(lgt - mx);
    float den = ex;
    #pragma unroll
    for (int mk = 1; mk <= 8; mk <<= 1) den += __shfl_xor(den, mk, 16);
    float wq = ex / den;
    float s0 = 0.f, s1 = 0.f, s2 = 0.f, s3 = 0.f;
    #pragma unroll
    for (int i = 0; i < 16; i++) {
        float wi = __shfl(wq, i, 16);
        int si = __shfl(src, i, 16);
        u16x4 v = *(const u16x4*)(V + (size_t)si * 128 + HALF * 64 + q * 4);
        s0 = fmaf(wi, bf2f(v[0]), s0);
        s1 = fmaf(wi, bf2f(v[1]), s1);
        s2 = fmaf(wi, bf2f(v[2]), s2);
        s3 = fmaf(wi, bf2f(v[3]), s3);
    }
    u16x4 o;
    o[0] = f2bf(s0); o[1] = f2bf(s1); o[2] = f2bf(s2); o[3] = f2bf(s3);
    __builtin_nontemporal_store(o, (u16x4*)(agg + (size_t)node * 128 + HALF * 64 + q * 4));
}

// ---------------- GRU: pre-GEMM (attend/fc2 on aggregated vec) + ELU -> ctx,
//                  GRU GEMMs, gates; FRONT: aD/bS dots; FINAL: avg+lin+gelu --------
template<int FRONT, int FINAL>
__global__ __launch_bounds__(256) void k_gru(
    const unsigned short* __restrict__ agg,
    const unsigned short* __restrict__ Bpre, const float* __restrict__ bpre,
    const unsigned short* __restrict__ hBf,
    const unsigned short* __restrict__ Bih, const unsigned short* __restrict__ Bhh,
    const float* __restrict__ bih, const float* __restrict__ bhh,
    const float* __restrict__ hprevF, float* __restrict__ houtF,
    unsigned short* __restrict__ houtBf,
    const float* __restrict__ w2att, float* __restrict__ aDOut, float* __restrict__ bSOut,
    const float* __restrict__ as0, const float* __restrict__ as1,
    const unsigned short* __restrict__ Blin, const float* __restrict__ linb,
    float* __restrict__ avgOut, float* __restrict__ outF)
{
    __shared__ unsigned short ctxS[16][136];
    const int tid = threadIdx.x, l = tid & 63, w = tid >> 6;
    const int lr = l & 15, lg = l >> 4;
    const int m0 = blockIdx.x * 16;

    // ---- pre-GEMM: ctx = elu(agg @ Wpre^T + bpre) ----
    f32x4 accp[2] = {};
    #pragma unroll
    for (int ko = 0; ko < 4; ko++) {
        short8 af = *(const short8*)(agg + (size_t)(m0 + lr) * 128 + ko * 32 + lg * 8);
        #pragma unroll
        for (int i = 0; i < 2; i++) {
            int t = w * 2 + i;
            short8 bf = *(const short8*)(Bpre + ((size_t)(t * 4 + ko) * 64 + l) * 8);
            accp[i] = __builtin_amdgcn_mfma_f32_16x16x32_bf16(af, bf, accp[i], 0, 0, 0);
        }
    }
    #pragma unroll
    for (int i = 0; i < 2; i++) {
        int col = (w * 2 + i) * 16 + lr;
        float bb = bpre[col];
        #pragma unroll
        for (int r = 0; r < 4; r++)
            ctxS[lg * 4 + r][col] = f2bf(elu_(accp[i][r] + bb));
    }
    __syncthreads();

    // ---- GRU GEMMs ----
    f32x4 acc[12] = {};
    #pragma unroll
    for (int ko = 0; ko < 4; ko++) {
        short8 afc = *(const short8*)&ctxS[lr][ko * 32 + lg * 8];
        short8 afh = *(const short8*)(hBf + (size_t)(m0 + lr) * 128 + ko * 32 + lg * 8);
        #pragma unroll
        for (int i2 = 0; i2 < 6; i2++) {
            short8 bf = *(const short8*)(Bih + ((size_t)((w + 4 * i2) * 4 + ko) * 64 + l) * 8);
            acc[i2] = __builtin_amdgcn_mfma_f32_16x16x32_bf16(afc, bf, acc[i2], 0, 0, 0);
        }
        #pragma unroll
        for (int i2 = 0; i2 < 6; i2++) {
            short8 bf = *(const short8*)(Bhh + ((size_t)((w + 4 * i2) * 4 + ko) * 64 + l) * 8);
            acc[6 + i2] = __builtin_amdgcn_mfma_f32_16x16x32_bf16(afh, bf, acc[6 + i2], 0, 0, 0);
        }
    }
    // ---- gates (fragment domain) ----
    float hov[2][4];
    #pragma unroll
    for (int i = 0; i < 2; i++) {
        const int c = (w + 4 * i) * 16 + lr;
        const float br = bih[c] + bhh[c];
        const float bz = bih[c + 128] + bhh[c + 128];
        const float bin_ = bih[c + 256];
        const float bhn = bhh[c + 256];
        #pragma unroll
        for (int r = 0; r < 4; r++) {
            const int row = m0 + lg * 4 + r;
            float rg = sigmoidf_(acc[i][r] + acc[6 + i][r] + br);
            float zg = sigmoidf_(acc[i + 2][r] + acc[8 + i][r] + bz);
            float ng = tanhf_(acc[i + 4][r] + bin_ + rg * (acc[10 + i][r] + bhn));
            float hp = __builtin_nontemporal_load(hprevF + (size_t)row * 128 + c);
            float ho = fmaf(zg, hp - ng, ng);
            hov[i][r] = ho;
            __builtin_nontemporal_store(ho, houtF + (size_t)row * 128 + c);
            if (FINAL == 0) houtBf[(size_t)row * 128 + c] = f2bf(ho);
        }
    }

    if (FRONT) {
        __syncthreads();
        #pragma unroll
        for (int i = 0; i < 2; i++) {
            const int c = (w + 4 * i) * 16 + lr;
            #pragma unroll
            for (int r = 0; r < 4; r++) ctxS[lg * 4 + r][c] = f2bf(hov[i][r]);
        }
        __syncthreads();
        {
            int row = tid >> 4, q = tid & 15;
            short8 hv = *(const short8*)&ctxS[row][q * 8];
            float pa = 0.f, pb = 0.f;
            #pragma unroll
            for (int j = 0; j < 8; j++) {
                float x = bf2f((unsigned short)hv[j]);
                pa = fmaf(x, w2att[q * 8 + j], pa);
                pb = fmaf(x, w2att[128 + q * 8 + j], pb);
            }
            #pragma unroll
            for (int m = 1; m <= 8; m <<= 1) {
                pa += __shfl_xor(pa, m, 16);
                pb += __shfl_xor(pb, m, 16);
            }
            if (q == 0) { aDOut[m0 + row] = pa; bSOut[m0 + row] = pb; }
        }
    }

    if (FINAL) {
        __syncthreads();
        #pragma unroll
        for (int i = 0; i < 2; i++) {
            const int c = (w + 4 * i) * 16 + lr;
            #pragma unroll
            for (int r = 0; r < 4; r++) {
                const int grow = m0 + lg * 4 + r;
                float x0 = __builtin_nontemporal_load(as0 + (size_t)grow * 128 + c);
                float x1 = __builtin_nontemporal_load(as1 + (size_t)grow * 128 + c);
                float av = (x0 + x1 + hov[i][r]) * (1.f / 3.f);
                __builtin_nontemporal_store(av, avgOut + (size_t)grow * 128 + c);
                ctxS[lg * 4 + r][c] = f2bf(av);
            }
        }
        __syncthreads();
        f32x4 acc2[2] = {};
        #pragma unroll
        for (int ko = 0; ko < 4; ko++) {
            short8 af = *(const short8*)&ctxS[lr][ko * 32 + lg * 8];
            #pragma unroll
            for (int i = 0; i < 2; i++) {
                int t = w * 2 + i;
                short8 bf = *(const short8*)(Blin + ((size_t)(t * 4 + ko) * 64 + l) * 8);
                acc2[i] = __builtin_amdgcn_mfma_f32_16x16x32_bf16(af, bf, acc2[i], 0, 0, 0);
            }
        }
        #pragma unroll
        for (int i = 0; i < 2; i++) {
            int col = (w * 2 + i) * 16 + lr;
            float bb = linb[col];
            #pragma unroll
            for (int r = 0; r < 4; r++) {
                float vv = acc2[i][r] + bb;
                vv = 0.5f * vv * (1.f + erff(vv * 0.70710678118654752f));
                __builtin_nontemporal_store(vv, outF + (size_t)(m0 + lg * 4 + r) * 128 + col);
            }
        }
    }
}

extern "C" void kernel_launch(void* const* d_in, const int* in_sizes, int n_in,
                              void* d_out, int out_size, void* d_ws, size_t ws_size,
                              hipStream_t stream) {
    const float* atom     = (const float*)d_in[0];
    const int*   esrc     = (const int*)d_in[1];
    const float* bond     = (const float*)d_in[3];
    const float* fc1_w    = (const float*)d_in[4];
    const float* fc1_b    = (const float*)d_in[5];
    const float* fc2_w    = (const float*)d_in[6];
    const float* fc2_b    = (const float*)d_in[7];
    const float* att_w    = (const float*)d_in[8];
    const float* att_b    = (const float*)d_in[9];
    const float* attend_w = (const float*)d_in[10];
    const float* attend_b = (const float*)d_in[11];
    const float* gih1     = (const float*)d_in[12];
    const float* ghh1     = (const float*)d_in[13];
    const float* bih1     = (const float*)d_in[14];
    const float* bhh1     = (const float*)d_in[15];
    const float* fc1v2_w  = (const float*)d_in[16];
    const float* fc1v2_b  = (const float*)d_in[17];
    const float* fc2v2_w  = (const float*)d_in[18];
    const float* fc2v2_b  = (const float*)d_in[19];
    const float* gih2     = (const float*)d_in[20];
    const float* ghh2     = (const float*)d_in[21];
    const float* bih2     = (const float*)d_in[22];
    const float* bhh2     = (const float*)d_in[23];
    const float* lin_w    = (const float*)d_in[24];
    const float* lin_b    = (const float*)d_in[25];

    char* wsb = (char*)d_ws;
    size_t off = 0;
    auto allocB = [&](size_t bytes) {
        size_t o = off; off = (off + bytes + 255) & ~(size_t)255; return o;
    };
    unsigned short* Bfc1   = (unsigned short*)(wsb + allocB(128 * 128 * 2));
    unsigned short* Batt   = (unsigned short*)(wsb + allocB(128 * 128 * 2));
    unsigned short* BW2a   = (unsigned short*)(wsb + allocB(128 * 128 * 2));
    unsigned short* BW2b   = (unsigned short*)(wsb + allocB(512 * 8 * 2));
    unsigned short* Bgih1  = (unsigned short*)(wsb + allocB(384 * 128 * 2));
    unsigned short* Bghh1  = (unsigned short*)(wsb + allocB(384 * 128 * 2));
    unsigned short* Bfc2v2 = (unsigned short*)(wsb + allocB(128 * 128 * 2));
    unsigned short* Bgih2  = (unsigned short*)(wsb + allocB(384 * 128 * 2));
    unsigned short* Bghh2  = (unsigned short*)(wsb + allocB(384 * 128 * 2));
    unsigned short* Blin   = (unsigned short*)(wsb + allocB(128 * 128 * 2));
    unsigned short* naBf   = (unsigned short*)(wsb + allocB((size_t)NN * 128 * 2));
    unsigned short* Ubf    = (unsigned short*)(wsb + allocB((size_t)NN * 128 * 2));
    unsigned short* aggBf  = (unsigned short*)(wsb + allocB((size_t)NN * 128 * 2));
    unsigned short* h1Bf   = (unsigned short*)(wsb + allocB((size_t)NN * 128 * 2));
    unsigned short* h2Bf   = (unsigned short*)(wsb + allocB((size_t)NN * 128 * 2));
    float* logits = (float*)(wsb + allocB((size_t)EE * 4));
    float* adst   = (float*)(wsb + allocB((size_t)NN * 4));
    float* aD     = (float*)(wsb + allocB((size_t)NN * 4));
    float* bS     = (float*)(wsb + allocB((size_t)NN * 4));
    (void)ws_size;

    float* out0 = (float*)d_out;
    float* as0  = out0 + (size_t)NN * 128;
    float* as1  = as0 + (size_t)NN * 128;
    float* as2  = as1 + (size_t)NN * 128;
    float* g0   = out0 + (size_t)4 * NN * 128;
    float* avg  = out0 + (size_t)5 * NN * 128;

    PackArgs pa;
    pa.d[0] = { fc1_w,    Bfc1,   128, 128, 0 };
    pa.d[1] = { attend_w, Batt,   128, 128, 0 };
    pa.d[2] = { fc2_w,    BW2a,   128, 144, 0 };
    pa.d[3] = { gih1,     Bgih1,  384, 128, 0 };
    pa.d[4] = { ghh1,     Bghh1,  384, 128, 0 };
    pa.d[5] = { fc2v2_w,  Bfc2v2, 128, 128, 0 };
    pa.d[6] = { gih2,     Bgih2,  384, 128, 0 };
    pa.d[7] = { ghh2,     Bghh2,  384, 128, 0 };
    pa.d[8] = { lin_w,    Blin,   128, 128, 0 };
    pa.d[9] = { fc2_w,    BW2b,   0,   0,   1 };
    k_pack<<<dim3(24, 10), 256, 0, stream>>>(pa);

    const int GB = NN / 16;  // 1250

    // ---- V1 ----
    k_v1_front<<<GB, 256, 0, stream>>>(atom, Bfc1, BW2a, fc1_b, fc2_b, att_w,
                                       g0, naBf, Ubf, adst);
    k_logits_v1<<<NN / 4, 256, 0, stream>>>(Ubf, esrc, bond, BW2b, att_w, att_b,
                                            adst, logits);
    k_agg<0, 0><<<GB, 256, 0, stream>>>(logits, nullptr, nullptr, nullptr, esrc, naBf, aggBf);
    k_agg<0, 1><<<GB, 256, 0, stream>>>(logits, nullptr, nullptr, nullptr, esrc, naBf, aggBf);
    k_gru<1, 0><<<GB, 256, 0, stream>>>(
        aggBf, Batt, attend_b,
        naBf, Bgih1, Bghh1, bih1, bhh1, g0, as0, h1Bf,
        fc1v2_w, aD, bS,
        nullptr, nullptr, nullptr, nullptr, nullptr, nullptr);

    // ---- V2 layer 2 ----
    k_agg<1, 0><<<GB, 256, 0, stream>>>(nullptr, aD, bS, fc1v2_b, esrc, h1Bf, aggBf);
    k_agg<1, 1><<<GB, 256, 0, stream>>>(nullptr, aD, bS, fc1v2_b, esrc, h1Bf, aggBf);
    k_gru<1, 0><<<GB, 256, 0, stream>>>(
        aggBf, Bfc2v2, fc2v2_b,
        h1Bf, Bgih2, Bghh2, bih2, bhh2, as0, as1, h2Bf,
        fc1v2_w, aD, bS,
        nullptr, nullptr, nullptr, nullptr, nullptr, nullptr);

    // ---- V2 layer 3 + final ----
    k_agg<1, 0><<<GB, 256, 0, stream>>>(nullptr, aD, bS, fc1v2_b, esrc, h2Bf, aggBf);
    k_agg<1, 1><<<GB, 256, 0, stream>>>(nullptr, aD, bS, fc1v2_b, esrc, h2Bf, aggBf);
    k_gru<0, 1><<<GB, 256, 0, stream>>>(
        aggBf, Bfc2v2, fc2v2_b,
        h2Bf, Bgih2, Bghh2, bih2, bhh2, as1, as2, nullptr,
        nullptr, nullptr, nullptr,
        as0, as1, Blin, lin_b, avg, out0);
}